// Round 4
// baseline (1059.367 us; speedup 1.0000x reference)
//
#include <hip/hip_runtime.h>

#define RC       6144       // rows = cols = 6144
#define OCSTRIDE 18432      // IC_N*9 floats per oc slice
#define NB       256        // grid blocks (1 per CU -> co-residency guaranteed)
#define NT       512        // threads per block (8 waves)
#define RPB      24         // rows per block (256*24 = 6144)
#define UNSCALE  1.52587890625e-05f   // 2^-16 cancels fp8 256x encode scale per iter
#define NBAR     24

typedef float v2f __attribute__((ext_vector_type(2)));

struct Ctrl {
    int   cnt[NBAR];
    float sig_dot;
    float sig_vsq;
    int   pad[6];
};

__device__ __forceinline__ float wave_reduce(float x) {
#pragma unroll
    for (int off = 32; off > 0; off >>= 1) x += __shfl_down(x, off, 64);
    return x;
}

__device__ __forceinline__ float dot8(uint2 w, float4 ua, float4 ub) {
    v2f f01 = __builtin_amdgcn_cvt_pk_f32_fp8(w.x, false);
    v2f f23 = __builtin_amdgcn_cvt_pk_f32_fp8(w.x, true);
    v2f f45 = __builtin_amdgcn_cvt_pk_f32_fp8(w.y, false);
    v2f f67 = __builtin_amdgcn_cvt_pk_f32_fp8(w.y, true);
    return f01.x*ua.x + f01.y*ua.y + f23.x*ua.z + f23.y*ua.w
         + f45.x*ub.x + f45.y*ub.y + f67.x*ub.z + f67.y*ub.w;
}

__global__ __launch_bounds__(64) void init_kernel(Ctrl* c) {
    if (threadIdx.x < NBAR) c->cnt[threadIdx.x] = 0;
    if (threadIdx.x == 0) { c->sig_dot = 0.f; c->sig_vsq = 0.f; }
}

// one-shot grid barrier: each counter used exactly once per launch
__device__ __forceinline__ void grid_barrier(int* cnt) {
    __syncthreads();
    if (threadIdx.x == 0) {
        __hip_atomic_fetch_add(cnt, 1, __ATOMIC_ACQ_REL, __HIP_MEMORY_SCOPE_AGENT);
        while (__hip_atomic_load(cnt, __ATOMIC_ACQUIRE, __HIP_MEMORY_SCOPE_AGENT) < NB)
            __builtin_amdgcn_s_sleep(2);
    }
    __syncthreads();
}

__global__ __launch_bounds__(NT) void fused_kernel(
    const float* __restrict__ conv, const float* __restrict__ u_in,
    unsigned char* __restrict__ Wq, float* __restrict__ ub0,
    float* __restrict__ ub1, Ctrl* __restrict__ ctrl, float* __restrict__ out)
{
    __shared__ float u_lds[RC];          // 24 KB
    __shared__ float v_lds[RPB];
    __shared__ float sred[8];
    __shared__ float red3[RPB][8];
    __shared__ float sbc;

    const int tid  = threadIdx.x;
    const int lane = tid & 63;
    const int wid  = tid >> 6;
    const int b    = blockIdx.x;
    const int r0   = b * RPB;

    // ---------------- phase 0: convert fp32 -> fp8 e4m3 (x256), permuted ----
    // Wq[r][c], r=oc*3+hh, c=ic*3+ww. thread writes 8 consecutive fp8 (8B store)
#pragma unroll 4
    for (int k = 0; k < 36; ++k) {
        const int t  = b * NT + tid + k * (NB * NT);   // < 4718592
        const int r  = t / 768;                        // 768 = RC/8
        const int c0 = (t - r * 768) * 8;
        const int oc = r / 3, hh = r - oc * 3;
        const float* base = conv + (size_t)oc * OCSTRIDE + hh * 3;
        float f[8];
#pragma unroll
        for (int e = 0; e < 8; ++e) {
            const int c  = c0 + e;
            const int ic = c / 3, ww = c - 3 * ic;
            f[e] = base[ic * 9 + ww] * 256.0f;
        }
        int lo = __builtin_amdgcn_cvt_pk_fp8_f32(f[0], f[1], 0, false);
        lo     = __builtin_amdgcn_cvt_pk_fp8_f32(f[2], f[3], lo, true);
        int hi = __builtin_amdgcn_cvt_pk_fp8_f32(f[4], f[5], 0, false);
        hi     = __builtin_amdgcn_cvt_pk_fp8_f32(f[6], f[7], hi, true);
        *reinterpret_cast<uint2*>(Wq + (size_t)t * 8) =
            make_uint2((unsigned)lo, (unsigned)hi);
    }

    int bar = 0;

    // ---------------- 10 power iterations, 2 grid barriers each -------------
    for (int it = 0; it < 10; ++it) {
        // stage u_cur into LDS; zero this block's 24-col slice of u_next
        const float* usrc = (it == 0) ? u_in : ((it & 1) ? ub0 : ub1);
        float*       unxt = (it & 1) ? ub1 : ub0;
#pragma unroll
        for (int k = 0; k < 3; ++k) {
            const int i4 = tid + k * NT;
            *reinterpret_cast<float4*>(u_lds + i4 * 4) =
                *reinterpret_cast<const float4*>(usrc + i4 * 4);
        }
        if (tid < RPB) unxt[r0 + tid] = 0.f;
        grid_barrier(&ctrl->cnt[bar++]);   // all staged + all slices zeroed

        // phase A: v[r] = Wq[r,:] . u  for this block's 24 rows (wave -> 3 rows)
        {
            const unsigned char* wr = Wq + (size_t)(r0 + wid * 3) * RC;
            float a0 = 0.f, a1 = 0.f, a2 = 0.f;
#pragma unroll
            for (int ch = 0; ch < 12; ++ch) {
                const int c = ch * 512 + lane * 8;
                const float4 ua = *reinterpret_cast<const float4*>(u_lds + c);
                const float4 ub = *reinterpret_cast<const float4*>(u_lds + c + 4);
                const uint2 wA = *reinterpret_cast<const uint2*>(wr + c);
                const uint2 wB = *reinterpret_cast<const uint2*>(wr + RC + c);
                const uint2 wC = *reinterpret_cast<const uint2*>(wr + 2 * RC + c);
                a0 += dot8(wA, ua, ub);
                a1 += dot8(wB, ua, ub);
                a2 += dot8(wC, ua, ub);
            }
            a0 = wave_reduce(a0); a1 = wave_reduce(a1); a2 = wave_reduce(a2);
            if (lane == 0) {
                v_lds[wid * 3 + 0] = a0 * UNSCALE;
                v_lds[wid * 3 + 1] = a1 * UNSCALE;
                v_lds[wid * 3 + 2] = a2 * UNSCALE;
            }
        }
        __syncthreads();

        // phase B: u'[c] += sum_{r local} Wq[r][c] * v[r]  (rows L1/L2-hot)
        {
            float acc[12];
#pragma unroll
            for (int e = 0; e < 12; ++e) acc[e] = 0.f;
            const unsigned char* wb = Wq + (size_t)r0 * RC;
#pragma unroll
            for (int s = 0; s < 3; ++s) {
                const int c0 = s * 2048 + tid * 4;
#pragma unroll 6
                for (int r = 0; r < RPB; ++r) {
                    const unsigned w =
                        *reinterpret_cast<const unsigned*>(wb + (size_t)r * RC + c0);
                    const v2f f01 = __builtin_amdgcn_cvt_pk_f32_fp8(w, false);
                    const v2f f23 = __builtin_amdgcn_cvt_pk_f32_fp8(w, true);
                    const float vv = v_lds[r];
                    acc[s * 4 + 0] += f01.x * vv;
                    acc[s * 4 + 1] += f01.y * vv;
                    acc[s * 4 + 2] += f23.x * vv;
                    acc[s * 4 + 3] += f23.y * vv;
                }
            }
#pragma unroll
            for (int s = 0; s < 3; ++s) {
                const int c0 = s * 2048 + tid * 4;
                atomicAdd(&unxt[c0 + 0], acc[s * 4 + 0]);
                atomicAdd(&unxt[c0 + 1], acc[s * 4 + 1]);
                atomicAdd(&unxt[c0 + 2], acc[s * 4 + 2]);
                atomicAdd(&unxt[c0 + 3], acc[s * 4 + 3]);
            }
        }
        grid_barrier(&ctrl->cnt[bar++]);   // u_next complete
    }

    // ---------------- final: sigma = 3 * (v/||v||) . (W * u/||u||) -----------
    // u_final = ub1 (iter 9 wrote ub[9&1]); v (iter 9) still in v_lds.
    {
        float sq = 0.f;
#pragma unroll
        for (int k = 0; k < 3; ++k) {
            const int i4 = tid + k * NT;
            const float4 q = *reinterpret_cast<const float4*>(ub1 + i4 * 4);
            *reinterpret_cast<float4*>(u_lds + i4 * 4) = q;
            sq += q.x * q.x + q.y * q.y + q.z * q.z + q.w * q.w;
        }
        sq = wave_reduce(sq);
        if (lane == 0) sred[wid] = sq;
        __syncthreads();
        if (tid == 0) {
            float s = 0.f;
#pragma unroll
            for (int w = 0; w < 8; ++w) s += sred[w];
            sbc = rsqrtf(s);
        }
        __syncthreads();
        const float uscale = sbc;

        // fp32 matvec over ORIGINAL conv for this block's 8 oc (24 rows)
        const int oc0 = b * 8;
        for (int ocl = 0; ocl < 8; ++ocl) {
            const float* base = conv + (size_t)(oc0 + ocl) * OCSTRIDE;
            const float4* p4  = reinterpret_cast<const float4*>(base + tid * 36);
            const float4* q12 = reinterpret_cast<const float4*>(u_lds + 12 * tid);
            float uv[12];
#pragma unroll
            for (int k = 0; k < 3; ++k) {
                const float4 q = q12[k];
                uv[4 * k] = q.x; uv[4 * k + 1] = q.y;
                uv[4 * k + 2] = q.z; uv[4 * k + 3] = q.w;
            }
            float acc0 = 0.f, acc1 = 0.f, acc2 = 0.f;
#pragma unroll
            for (int j = 0; j < 9; ++j) {
                const float4 q = p4[j];
                const float el[4] = {q.x, q.y, q.z, q.w};
#pragma unroll
                for (int e = 0; e < 4; ++e) {
                    const int m   = 4 * j + e;
                    const int icl = m / 9;
                    const int rem = m - 9 * icl;
                    const int hh  = rem / 3;
                    const int ww  = rem - 3 * hh;
                    const float pv = el[e] * uv[icl * 3 + ww];
                    if (hh == 0) acc0 += pv;
                    else if (hh == 1) acc1 += pv;
                    else acc2 += pv;
                }
            }
            acc0 = wave_reduce(acc0);
            acc1 = wave_reduce(acc1);
            acc2 = wave_reduce(acc2);
            if (lane == 0) {
                red3[ocl * 3 + 0][wid] = acc0;
                red3[ocl * 3 + 1][wid] = acc1;
                red3[ocl * 3 + 2][wid] = acc2;
            }
        }
        __syncthreads();

        float d = 0.f, vs = 0.f;
        if (tid < RPB) {
            float tv = 0.f;
#pragma unroll
            for (int w = 0; w < 8; ++w) tv += red3[tid][w];
            tv *= uscale;                       // t[r] = W[r,:] . u_hat
            const float vv = v_lds[tid];
            d  = vv * tv;
            vs = vv * vv;
        }
        if (wid == 0) {
            d  = wave_reduce(d);
            vs = wave_reduce(vs);
            if (lane == 0) {
                atomicAdd(&ctrl->sig_dot, d);
                atomicAdd(&ctrl->sig_vsq, vs);
            }
        }
    }
    grid_barrier(&ctrl->cnt[bar++]);

    if (b == 0 && tid == 0) {
        const float d  = __hip_atomic_load(&ctrl->sig_dot, __ATOMIC_RELAXED,
                                           __HIP_MEMORY_SCOPE_AGENT);
        const float vs = __hip_atomic_load(&ctrl->sig_vsq, __ATOMIC_RELAXED,
                                           __HIP_MEMORY_SCOPE_AGENT);
        out[0] = 3.0f * d * rsqrtf(vs);
    }
}

extern "C" void kernel_launch(void* const* d_in, const int* in_sizes, int n_in,
                              void* d_out, int out_size, void* d_ws, size_t ws_size,
                              hipStream_t stream)
{
    const float* conv = (const float*)d_in[0];   // [2048,2048,3,3] fp32
    const float* u_in = (const float*)d_in[1];   // [1,6144] fp32, unit norm
    float* out = (float*)d_out;

    // ws layout (bytes): ub0[24576] | ub1[24576] | Ctrl[128] | Wq[37748736]
    const size_t OFF_UB1  = (size_t)RC * sizeof(float);
    const size_t OFF_CTRL = 2 * OFF_UB1;
    const size_t OFF_WQ   = OFF_CTRL + 128;
    const size_t needed   = OFF_WQ + (size_t)RC * RC;
    if (ws_size < needed) return;

    char* ws = (char*)d_ws;
    float* ub0         = (float*)ws;
    float* ub1         = (float*)(ws + OFF_UB1);
    Ctrl*  ctrl        = (Ctrl*)(ws + OFF_CTRL);
    unsigned char* Wq  = (unsigned char*)(ws + OFF_WQ);

    init_kernel<<<1, 64, 0, stream>>>(ctrl);
    fused_kernel<<<NB, NT, 0, stream>>>(conv, u_in, Wq, ub0, ub1, ctrl, out);
}